// Round 3
// baseline (54.915 us; speedup 1.0000x reference)
//
#include <hip/hip_runtime.h>
#include <math.h>

// Problem constants
#define N_  32
#define C_  256
#define K_  6
#define M_  22
#define HO_ 17
#define P_  484            // 22*22
#define ZP_ 36             // 6*6

static constexpr int OUT0_SZ = N_ * HO_ * HO_;        // 9248
static constexpr int XF_OFF  = OUT0_SZ;               // xf starts here
static constexpr int XF_SZ   = N_ * C_ * P_;          // 3964928
static constexpr int ZF_OFF  = XF_OFF + XF_SZ;        // 3974176

// ---------------------------------------------------------------------------
// Kernel 1 (fused): branch conv (recomputed in-register) + Bhattacharyya.
// Block = (n, i) output row, 544 blocks; 256 threads = one channel each.
//  - stages x[n] rows i..i+5 (3ch x 6 x 22 = 396 floats) + z[n] (108) in LDS
//  - thread c computes zf[n,c,:] and xf[n,c,rows i..i+5] in registers
//    (3 FMA + ReLU each), writes the xf/zf outputs it owns (row-ownership:
//    block i writes row i; block 16 also writes rows 17..21; block 0 writes zf)
//  - sliding-window register accumulation of the 17-wide score row,
//    butterfly + LDS reduce over 256 channels
//  - emits per-block (sum, sumsq) of its 17 scores into ws for BN
// ---------------------------------------------------------------------------
__global__ __launch_bounds__(256) void k_fused(
    const float* __restrict__ z, const float* __restrict__ x,
    const float* __restrict__ Wb, const float* __restrict__ bb,
    const float* __restrict__ wv,
    float* __restrict__ out, float* __restrict__ ws)
{
    const int blk = blockIdx.x;
    const int n = blk / HO_;
    const int i = blk % HO_;
    const int c = threadIdx.x;

    __shared__ float xs[3][6][22];   // x[n], 3 ch, rows i..i+5
    __shared__ float zs[3 * ZP_];    // z[n]
    __shared__ float red[4][HO_];
    __shared__ float sc[HO_];

    // ---- stage inputs ----
    const float* xp = x + (size_t)n * (3 * P_);
    for (int t = c; t < 3 * 6 * 22; t += 256) {
        const int ch = t / 132;
        const int rr = (t % 132) / 22;
        const int u  = t % 22;
        xs[ch][rr][u] = xp[ch * P_ + (i + rr) * 22 + u];
    }
    const float* zp = z + (size_t)n * (3 * ZP_);
    for (int t = c; t < 3 * ZP_; t += 256) zs[t] = zp[t];
    __syncthreads();

    // per-channel weights
    const float w0 = Wb[c * 3 + 0];
    const float w1 = Wb[c * 3 + 1];
    const float w2 = Wb[c * 3 + 2];
    const float bi = bb[c];
    const float wc = wv[c] * (1.f / 36.f);

    // ---- z-side: zf + weighted sqrt, in registers ----
    float szv[ZP_];
    float* zdst = out + ZF_OFF + (size_t)(n * C_ + c) * ZP_;
    if (i == 0) {
#pragma unroll
        for (int k = 0; k < ZP_; ++k) {
            const float v = fmaxf(0.f,
                fmaf(zs[k], w0, fmaf(zs[ZP_ + k], w1, fmaf(zs[2 * ZP_ + k], w2, bi))));
            zdst[k] = v;
            szv[k] = wc * sqrtf(v);
        }
    } else {
#pragma unroll
        for (int k = 0; k < ZP_; ++k) {
            const float v = fmaxf(0.f,
                fmaf(zs[k], w0, fmaf(zs[ZP_ + k], w1, fmaf(zs[2 * ZP_ + k], w2, bi))));
            szv[k] = wc * sqrtf(v);
        }
    }

    // ---- x-side: 6 rows, conv + ReLU + sqrt in registers; sliding window ----
    float acc[HO_];
#pragma unroll
    for (int j = 0; j < HO_; ++j) acc[j] = 0.f;

    const bool wr_all = (i == 16);
    float* xbase = out + XF_OFF + (size_t)(n * C_ + c) * P_;

#pragma unroll
    for (int r = 0; r < 6; ++r) {
        const bool wr = (r == 0) || wr_all;   // row ownership (uniform per block)
        float* rdst = xbase + (i + r) * 22;
        float sq[22];
#pragma unroll
        for (int u = 0; u < 22; ++u) {
            const float v = fmaxf(0.f,
                fmaf(xs[0][r][u], w0, fmaf(xs[1][r][u], w1, fmaf(xs[2][r][u], w2, bi))));
            if (wr) rdst[u] = v;
            sq[u] = sqrtf(v);
        }
#pragma unroll
        for (int kw = 0; kw < K_; ++kw) {
            const float s = szv[r * 6 + kw];
#pragma unroll
            for (int j = 0; j < HO_; ++j)
                acc[j] = fmaf(s, sq[j + kw], acc[j]);
        }
    }

    // ---- reduce over channels: 64-lane butterfly, then 4 waves via LDS ----
#pragma unroll
    for (int off = 1; off < 64; off <<= 1) {
#pragma unroll
        for (int j = 0; j < HO_; ++j)
            acc[j] += __shfl_xor(acc[j], off, 64);
    }
    const int wave = c >> 6;
    const int lane = c & 63;
    if (lane == 0) {
#pragma unroll
        for (int j = 0; j < HO_; ++j) red[wave][j] = acc[j];
    }
    __syncthreads();
    if (c < HO_) {
        const float v = red[0][c] + red[1][c] + red[2][c] + red[3][c];
        out[n * (HO_ * HO_) + i * HO_ + c] = v;
        sc[c] = v;
    }
    __syncthreads();
    if (c == 0) {
        float s = 0.f, q = 0.f;
#pragma unroll
        for (int j = 0; j < HO_; ++j) { s += sc[j]; q += sc[j] * sc[j]; }
        ws[blk * 2 + 0] = s;
        ws[blk * 2 + 1] = q;
    }
}

// ---------------------------------------------------------------------------
// Kernel 2: BN finalize. Reduces 544 (sum,sumsq) pairs in double, then
// normalizes the 9248 scores in place. Single block => deterministic.
// ---------------------------------------------------------------------------
__global__ __launch_bounds__(1024) void k_bn2(
    const float* __restrict__ gamma, const float* __restrict__ beta,
    float* __restrict__ out, const float* __restrict__ ws)
{
    constexpr int NB  = N_ * HO_;     // 544 blocks in K1
    constexpr int TOT = OUT0_SZ;      // 9248
    const int t = threadIdx.x;

    __shared__ double ds[16], dq[16];
    __shared__ float fp[2];

    double s = 0.0, q = 0.0;
    if (t < NB) { s = (double)ws[2 * t]; q = (double)ws[2 * t + 1]; }
#pragma unroll
    for (int off = 1; off < 64; off <<= 1) {
        s += __shfl_xor(s, off, 64);
        q += __shfl_xor(q, off, 64);
    }
    if ((t & 63) == 0) { ds[t >> 6] = s; dq[t >> 6] = q; }
    __syncthreads();
    if (t == 0) {
        double S = 0.0, Q = 0.0;
#pragma unroll
        for (int w = 0; w < 16; ++w) { S += ds[w]; Q += dq[w]; }
        const double mu  = S / (double)TOT;
        const double var = Q / (double)TOT - mu * mu;
        fp[0] = (float)mu;
        fp[1] = (float)((double)gamma[0] / sqrt(var + 1e-5));
    }
    __syncthreads();
    const float mu = fp[0], scale = fp[1], sh = beta[0];
    for (int idx = t; idx < TOT; idx += 1024)
        out[idx] = (out[idx] - mu) * scale + sh;
}

// ---------------------------------------------------------------------------
extern "C" void kernel_launch(void* const* d_in, const int* in_sizes, int n_in,
                              void* d_out, int out_size, void* d_ws, size_t ws_size,
                              hipStream_t stream) {
    const float* z     = (const float*)d_in[0];
    const float* x     = (const float*)d_in[1];
    const float* Wb    = (const float*)d_in[2];
    const float* bb    = (const float*)d_in[3];
    const float* wv    = (const float*)d_in[4];
    const float* gamma = (const float*)d_in[5];
    const float* beta  = (const float*)d_in[6];
    float* out = (float*)d_out;
    float* ws  = (float*)d_ws;

    k_fused<<<N_ * HO_, 256, 0, stream>>>(z, x, Wb, bb, wv, out, ws);
    k_bn2<<<1, 1024, 0, stream>>>(gamma, beta, out, ws);
}

// Round 4
// 24.883 us; speedup vs baseline: 2.2069x; 2.2069x over previous
//
#include <hip/hip_runtime.h>
#include <math.h>

// Problem constants
#define N_  32
#define C_  256
#define K_  6
#define M_  22
#define HO_ 17
#define P_  484            // 22*22
#define ZP_ 36             // 6*6

static constexpr int OUT0_SZ = N_ * HO_ * HO_;        // 9248
static constexpr int XF_OFF  = OUT0_SZ;               // xf starts here
static constexpr int XF_SZ   = N_ * C_ * P_;          // 3964928
static constexpr int ZF_OFF  = XF_OFF + XF_SZ;        // 3974176

static constexpr int CORR_BLOCKS = N_ * HO_;          // 544
static constexpr int CONV_BLOCKS = N_ * (C_ / 2);     // 4096 (one block = 2 channels)

// fast sqrt: raw v_sqrt_f32 (~1 ulp), plenty for the 6.9e-2 threshold
__device__ __forceinline__ float fsqrt(float x) { return __builtin_amdgcn_sqrtf(x); }

// DPP wave64 sum-reduction step: x += dpp_perm(x), invalid lanes contribute 0
#define DPP_ADD(x, ctrl)                                                      \
    (x) += __builtin_bit_cast(float, __builtin_amdgcn_update_dpp(             \
               0, __builtin_bit_cast(int, (x)), (ctrl), 0xF, 0xF, true))

// ---------------------------------------------------------------------------
// Fat kernel.
// blocks [0, 544):    correlation path. Block=(n,i). 256 thr = channel.
//   Recomputes branch conv in registers from LDS-staged x/z rows (no global
//   writes of xf/zf at all). Sliding-window 17-acc row, DPP wave reduce,
//   LDS cross-wave reduce, writes 17 scores + (sum,sumsq) to ws.
// blocks [544, 4640):  conv path. Block=(n,opair). Pure streaming conv+ReLU,
//   fully coalesced float4 writes of xf (121 f4/ch) and zf (9 f4/ch).
// ---------------------------------------------------------------------------
__global__ __launch_bounds__(256) void k_fat(
    const float* __restrict__ z, const float* __restrict__ x,
    const float* __restrict__ Wb, const float* __restrict__ bb,
    const float* __restrict__ wv,
    float* __restrict__ out, float* __restrict__ ws)
{
    const int blk = blockIdx.x;
    const int t   = threadIdx.x;

    if (blk >= CORR_BLOCKS) {
        // ---------------- conv path ----------------
        const int b     = blk - CORR_BLOCKS;
        const int n     = b >> 7;          // 128 opairs per n
        const int opair = b & 127;
        const int o     = opair * 2 + (t >> 7);
        const int t2    = t & 127;

        const float w0 = Wb[o * 3 + 0];
        const float w1 = Wb[o * 3 + 1];
        const float w2 = Wb[o * 3 + 2];
        const float bi = bb[o];

        if (t2 < 121) {
            const float4* xb = (const float4*)(x + (size_t)n * 3 * P_);
            float4 a = xb[t2];
            float4 b4 = xb[121 + t2];
            float4 c4 = xb[242 + t2];
            float4 r;
            r.x = fmaxf(0.f, fmaf(a.x, w0, fmaf(b4.x, w1, fmaf(c4.x, w2, bi))));
            r.y = fmaxf(0.f, fmaf(a.y, w0, fmaf(b4.y, w1, fmaf(c4.y, w2, bi))));
            r.z = fmaxf(0.f, fmaf(a.z, w0, fmaf(b4.z, w1, fmaf(c4.z, w2, bi))));
            r.w = fmaxf(0.f, fmaf(a.w, w0, fmaf(b4.w, w1, fmaf(c4.w, w2, bi))));
            ((float4*)(out + XF_OFF + (size_t)(n * C_ + o) * P_))[t2] = r;
        }
        if (t2 >= 119) {                  // 9 threads (119..127) cover zf
            const int t3 = t2 - 119;
            const float4* zb = (const float4*)(z + (size_t)n * 3 * ZP_);
            float4 a = zb[t3];
            float4 b4 = zb[9 + t3];
            float4 c4 = zb[18 + t3];
            float4 r;
            r.x = fmaxf(0.f, fmaf(a.x, w0, fmaf(b4.x, w1, fmaf(c4.x, w2, bi))));
            r.y = fmaxf(0.f, fmaf(a.y, w0, fmaf(b4.y, w1, fmaf(c4.y, w2, bi))));
            r.z = fmaxf(0.f, fmaf(a.z, w0, fmaf(b4.z, w1, fmaf(c4.z, w2, bi))));
            r.w = fmaxf(0.f, fmaf(a.w, w0, fmaf(b4.w, w1, fmaf(c4.w, w2, bi))));
            ((float4*)(out + ZF_OFF + (size_t)(n * C_ + o) * ZP_))[t3] = r;
        }
        return;
    }

    // ---------------- correlation path ----------------
    const int n = blk / HO_;
    const int i = blk % HO_;
    const int c = t;

    __shared__ float xs[3][6][22];   // x[n], 3 ch, rows i..i+5
    __shared__ float zs[3 * ZP_];    // z[n]
    __shared__ float red[4][HO_];
    __shared__ float sc[HO_];

    const float* xp = x + (size_t)n * (3 * P_);
    for (int u = c; u < 3 * 6 * 22; u += 256) {
        const int ch = u / 132;
        const int rr = (u % 132) / 22;
        const int uu = u % 22;
        xs[ch][rr][uu] = xp[ch * P_ + (i + rr) * 22 + uu];
    }
    const float* zp = z + (size_t)n * (3 * ZP_);
    for (int u = c; u < 3 * ZP_; u += 256) zs[u] = zp[u];
    __syncthreads();

    const float w0 = Wb[c * 3 + 0];
    const float w1 = Wb[c * 3 + 1];
    const float w2 = Wb[c * 3 + 2];
    const float bi = bb[c];
    const float wc = wv[c] * (1.f / 36.f);

    // z-side weighted sqrt, in registers
    float szv[ZP_];
#pragma unroll
    for (int k = 0; k < ZP_; ++k) {
        const float v = fmaxf(0.f,
            fmaf(zs[k], w0, fmaf(zs[ZP_ + k], w1, fmaf(zs[2 * ZP_ + k], w2, bi))));
        szv[k] = wc * fsqrt(v);
    }

    // x-side: 6 rows, conv + ReLU + sqrt in registers; sliding 17-wide window
    float acc[HO_];
#pragma unroll
    for (int j = 0; j < HO_; ++j) acc[j] = 0.f;

#pragma unroll
    for (int r = 0; r < 6; ++r) {
        float sq[22];
#pragma unroll
        for (int u = 0; u < 22; ++u) {
            const float v = fmaxf(0.f,
                fmaf(xs[0][r][u], w0, fmaf(xs[1][r][u], w1, fmaf(xs[2][r][u], w2, bi))));
            sq[u] = fsqrt(v);
        }
#pragma unroll
        for (int kw = 0; kw < K_; ++kw) {
            const float s = szv[r * 6 + kw];
#pragma unroll
            for (int j = 0; j < HO_; ++j)
                acc[j] = fmaf(s, sq[j + kw], acc[j]);
        }
    }

    // wave64 sum reduce via DPP (result lands in lane 63)
#pragma unroll
    for (int j = 0; j < HO_; ++j) {
        DPP_ADD(acc[j], 0x111);   // row_shr:1
        DPP_ADD(acc[j], 0x112);   // row_shr:2
        DPP_ADD(acc[j], 0x114);   // row_shr:4
        DPP_ADD(acc[j], 0x118);   // row_shr:8  -> lane15 of each row has row sum
        DPP_ADD(acc[j], 0x142);   // row_bcast:15
        DPP_ADD(acc[j], 0x143);   // row_bcast:31 -> lane63 has wave sum
    }
    const int wave = c >> 6;
    const int lane = c & 63;
    if (lane == 63) {
#pragma unroll
        for (int j = 0; j < HO_; ++j) red[wave][j] = acc[j];
    }
    __syncthreads();
    if (c < HO_) {
        const float v = red[0][c] + red[1][c] + red[2][c] + red[3][c];
        out[n * (HO_ * HO_) + i * HO_ + c] = v;
        sc[c] = v;
    }
    __syncthreads();
    if (c == 0) {
        float s = 0.f, q = 0.f;
#pragma unroll
        for (int j = 0; j < HO_; ++j) { s += sc[j]; q += sc[j] * sc[j]; }
        ws[blk * 2 + 0] = s;
        ws[blk * 2 + 1] = q;
    }
}

// ---------------------------------------------------------------------------
// BN finalize. Reduces 544 (sum,sumsq) pairs in double, then normalizes the
// 9248 scores in place. Single block => deterministic.
// ---------------------------------------------------------------------------
__global__ __launch_bounds__(1024) void k_bn2(
    const float* __restrict__ gamma, const float* __restrict__ beta,
    float* __restrict__ out, const float* __restrict__ ws)
{
    constexpr int NB  = CORR_BLOCKS;  // 544
    constexpr int TOT = OUT0_SZ;      // 9248
    const int t = threadIdx.x;

    __shared__ double ds[16], dq[16];
    __shared__ float fp[2];

    double s = 0.0, q = 0.0;
    if (t < NB) { s = (double)ws[2 * t]; q = (double)ws[2 * t + 1]; }
#pragma unroll
    for (int off = 1; off < 64; off <<= 1) {
        s += __shfl_xor(s, off, 64);
        q += __shfl_xor(q, off, 64);
    }
    if ((t & 63) == 0) { ds[t >> 6] = s; dq[t >> 6] = q; }
    __syncthreads();
    if (t == 0) {
        double S = 0.0, Q = 0.0;
#pragma unroll
        for (int w = 0; w < 16; ++w) { S += ds[w]; Q += dq[w]; }
        const double mu  = S / (double)TOT;
        const double var = Q / (double)TOT - mu * mu;
        fp[0] = (float)mu;
        fp[1] = (float)((double)gamma[0] / sqrt(var + 1e-5));
    }
    __syncthreads();
    const float mu = fp[0], scale = fp[1], sh = beta[0];
    for (int idx = t; idx < TOT; idx += 1024)
        out[idx] = (out[idx] - mu) * scale + sh;
}

// ---------------------------------------------------------------------------
extern "C" void kernel_launch(void* const* d_in, const int* in_sizes, int n_in,
                              void* d_out, int out_size, void* d_ws, size_t ws_size,
                              hipStream_t stream) {
    const float* z     = (const float*)d_in[0];
    const float* x     = (const float*)d_in[1];
    const float* Wb    = (const float*)d_in[2];
    const float* bb    = (const float*)d_in[3];
    const float* wv    = (const float*)d_in[4];
    const float* gamma = (const float*)d_in[5];
    const float* beta  = (const float*)d_in[6];
    float* out = (float*)d_out;
    float* ws  = (float*)d_ws;

    k_fat<<<CORR_BLOCKS + CONV_BLOCKS, 256, 0, stream>>>(z, x, Wb, bb, wv, out, ws);
    k_bn2<<<1, 1024, 0, stream>>>(gamma, beta, out, ws);
}